// Round 16
// baseline (479.587 us; speedup 1.0000x reference)
//
#include <hip/hip_runtime.h>
#include <math.h>

#define NS 1024
#define NV 99
#define NPTS 100
#define H 512

typedef __bf16 bf16x8 __attribute__((ext_vector_type(8)));
typedef __bf16 bf16x4 __attribute__((ext_vector_type(4)));
typedef float f32x4 __attribute__((ext_vector_type(4)));

// async 16B-per-lane global->LDS copy; LDS dest is wave-uniform base + lane*16
#define GLD_LDS16(gp, lp) __builtin_amdgcn_global_load_lds(                 \
    (const __attribute__((address_space(1))) void*)(gp),                    \
    (__attribute__((address_space(3))) void*)(lp), 16, 0, 0)
#define WAIT_VM0()   __builtin_amdgcn_s_waitcnt(0x0f70)   // vmcnt(0) only
#define WAIT_LGKM0() __builtin_amdgcn_s_waitcnt(0xc07f)   // lgkmcnt(0) only

// ---------------- K1: weight norm, wave-per-row, + folded s0 table ----------------
// Blocks 0..640: 4 weight rows per block (one wave per row, shfl_xor reduce,
// no LDS / no barriers). Blocks 641..838: the s0sin table (old k_s0).
// mod weights row-major; siren W1/W2 bf16 MFMA-fragment-swizzled:
// swz[((ct*16 + t)*64 + Q*16 + L)*8 + j] = W[ct*16+L][t*32+Q*8+j]
__global__ __launch_bounds__(256) void k_wnorm(
    const float* __restrict__ mv0, const float* __restrict__ mg0,
    const float* __restrict__ mv1, const float* __restrict__ mg1,
    const float* __restrict__ mv2, const float* __restrict__ mg2,
    const float* __restrict__ sv0, const float* __restrict__ sg0,
    const float* __restrict__ sb0,
    const float* __restrict__ sv1, const float* __restrict__ sg1,
    const float* __restrict__ sv2, const float* __restrict__ sg2,
    const float* __restrict__ dv,  const float* __restrict__ dg,
    float* __restrict__ wnM0, float* __restrict__ wnM1, float* __restrict__ wnM2,
    __bf16* __restrict__ W1s, __bf16* __restrict__ W2s, float* __restrict__ wnD,
    float* __restrict__ s0sin)
{
    const int b = blockIdx.x, tid = threadIdx.x;
    if (b >= 641) {   // folded k_s0
        int idx = (b - 641) * 256 + tid;
        if (idx < NV * H) {
            int p = idx >> 9, j = idx & 511;
            float v = sv0[j];
            float w = sg0[j] * v * rsqrtf(v * v);
            float t = (float)p / 99.0f;
            s0sin[idx] = __sinf(30.0f * (t * w + sb0[j]));
        }
        return;
    }
    const int rid = b * 4 + (tid >> 6);
    const int lane = tid & 63;
    if (rid >= 2563) return;

    const float* src; const float* g; int len, j;
    float* dstf = nullptr; __bf16* dstb = nullptr;
    if (rid < 512)       { j = rid;        src = mv0 + j*64;  g = mg0; dstf = wnM0 + j*64;  len = 64;  }
    else if (rid < 1024) { j = rid - 512;  src = mv1 + j*576; g = mg1; dstf = wnM1 + j*576; len = 576; }
    else if (rid < 1536) { j = rid - 1024; src = mv2 + j*576; g = mg2; dstf = wnM2 + j*576; len = 576; }
    else if (rid < 2048) { j = rid - 1536; src = sv1 + j*512; g = sg1; dstb = W1s;          len = 512; }
    else if (rid < 2560) { j = rid - 2048; src = sv2 + j*512; g = sg2; dstb = W2s;          len = 512; }
    else                 { j = rid - 2560; src = dv  + j*512; g = dg;  dstf = wnD + j*512;  len = 512; }

    float ss = 0.f;
    for (int k = lane; k < len; k += 64) { float v = src[k]; ss += v * v; }
#pragma unroll
    for (int o = 1; o < 64; o <<= 1) ss += __shfl_xor(ss, o, 64);
    const float sc = g[j] * rsqrtf(ss);

    if (dstb) {
        for (int k = lane; k < len; k += 64) {
            int f  = (j >> 4) * 16 + (k >> 5);
            int el = ((f * 64) + ((k >> 3) & 3) * 16 + (j & 15)) * 8 + (k & 7);
            dstb[el] = (__bf16)(src[k] * sc);
        }
    } else {
        for (int k = lane; k < len; k += 64) dstf[k] = src[k] * sc;
    }
}

// ---------------- K3: modulation branch, 4 strands per block (round-3 proven) ----------------
__global__ __launch_bounds__(256) void k_mod(
    const float* __restrict__ sf,
    const float* __restrict__ wnM0, const float* __restrict__ mb0,
    const float* __restrict__ wnM1, const float* __restrict__ mb1,
    const float* __restrict__ wnM2, const float* __restrict__ mb2,
    float* __restrict__ onem)
{
    const int g0 = blockIdx.x * 4, tid = threadIdx.x;
    __shared__ float z[4][576];   // [strand][64 feat | 512 hidden]

    for (int idx = tid; idx < 4 * 64; idx += 256)
        z[idx >> 6][idx & 63] = sf[(g0 + (idx >> 6)) * 64 + (idx & 63)];
    __syncthreads();

    float mreg[2][4];
    // ---- layer 0 (in=64) ----
#pragma unroll
    for (int r = 0; r < 2; ++r) {
        const int j = tid + 256 * r;
        const float* wr = wnM0 + j * 64;
        float acc[4] = {0.f, 0.f, 0.f, 0.f};
#pragma unroll
        for (int k = 0; k < 64; k += 4) {
            float4 w = *(const float4*)(wr + k);
#pragma unroll
            for (int g = 0; g < 4; ++g) {
                float4 zv = *(const float4*)&z[g][k];
                acc[g] += zv.x * w.x + zv.y * w.y + zv.z * w.z + zv.w * w.w;
            }
        }
        const float b = mb0[j];
#pragma unroll
        for (int g = 0; g < 4; ++g) {
            float a = acc[g] + b;
            float m = a / (1.f + __expf(-a));
            onem[(g0 + g) * H + j] = 1.f - m;
            mreg[r][g] = m;
        }
    }
    __syncthreads();
#pragma unroll
    for (int r = 0; r < 2; ++r)
#pragma unroll
        for (int g = 0; g < 4; ++g) z[g][64 + tid + 256 * r] = mreg[r][g];
    __syncthreads();

    // ---- layer 1 (in=576) ----
#pragma unroll
    for (int r = 0; r < 2; ++r) {
        const int j = tid + 256 * r;
        const float* wr = wnM1 + j * 576;
        float acc[4] = {0.f, 0.f, 0.f, 0.f};
        for (int k = 0; k < 576; k += 4) {
            float4 w = *(const float4*)(wr + k);
#pragma unroll
            for (int g = 0; g < 4; ++g) {
                float4 zv = *(const float4*)&z[g][k];
                acc[g] += zv.x * w.x + zv.y * w.y + zv.z * w.z + zv.w * w.w;
            }
        }
        const float b = mb1[j];
#pragma unroll
        for (int g = 0; g < 4; ++g) {
            float a = acc[g] + b;
            float m = a / (1.f + __expf(-a));
            onem[NS * H + (g0 + g) * H + j] = 1.f - m;
            mreg[r][g] = m;
        }
    }
    __syncthreads();
#pragma unroll
    for (int r = 0; r < 2; ++r)
#pragma unroll
        for (int g = 0; g < 4; ++g) z[g][64 + tid + 256 * r] = mreg[r][g];
    __syncthreads();

    // ---- layer 2 (in=576) ----
#pragma unroll
    for (int r = 0; r < 2; ++r) {
        const int j = tid + 256 * r;
        const float* wr = wnM2 + j * 576;
        float acc[4] = {0.f, 0.f, 0.f, 0.f};
        for (int k = 0; k < 576; k += 4) {
            float4 w = *(const float4*)(wr + k);
#pragma unroll
            for (int g = 0; g < 4; ++g) {
                float4 zv = *(const float4*)&z[g][k];
                acc[g] += zv.x * w.x + zv.y * w.y + zv.z * w.z + zv.w * w.w;
            }
        }
        const float b = mb2[j];
#pragma unroll
        for (int g = 0; g < 4; ++g) {
            float a = acc[g] + b;
            float m = a / (1.f + __expf(-a));
            onem[2 * NS * H + (g0 + g) * H + j] = 1.f - m;
        }
    }
}

// ---------------- K4: main fused siren layers 1,2 + decoder ----------------
// Round-10/15 structure with ONE change: per-block kb-order rotation
// (kb = (i + blockIdx&15) & 15). kb iterations are independent (disjoint
// output columns; per-kb accumulation untouched) -> BIT-IDENTICAL output,
// but co-resident blocks' DMA drains desynchronize and concurrent W reads
// spread across the full 1 MB instead of one shared 16 KB window.
__global__ __launch_bounds__(64, 1) void k_main(
    const __bf16* __restrict__ W1s, const __bf16* __restrict__ W2s,
    const float* __restrict__ wnD, const float* __restrict__ sb1,
    const float* __restrict__ sb2, const float* __restrict__ db,
    const float* __restrict__ s0sin, const float* __restrict__ onem,
    float* __restrict__ dirs)
{
    __shared__ __attribute__((aligned(16))) __bf16 h2p[32][520];  // 33280 B
    __shared__ __attribute__((aligned(16))) __bf16 wst[8192];     // 16 KB staging
    const int lane = threadIdx.x;
    const int L = lane & 15, Q = lane >> 4;
    const int base = blockIdx.x * 32;
    const int kb0 = blockIdx.x & 15;          // per-block phase offset
    const int r0 = base + L, r1 = r0 + 16;
    const int s0 = r0 / 99, p0 = r0 - s0 * 99;
    const int s1 = r1 / 99, p1 = r1 - s1 * 99;

    // ---- build layer-1 B-frags: Bh[t][j] = h1[r][t*32+Q*8+j] ----
    bf16x8 Bh0[16], Bh1[16];
    {
        const float* omA = onem + s0 * H;
        const float* tsA = s0sin + p0 * H;
        const float* omB = onem + s1 * H;
        const float* tsB = s0sin + p1 * H;
#pragma unroll
        for (int t = 0; t < 16; ++t) {
            const int k0 = t * 32 + Q * 8;
            f32x4 oa = *(const f32x4*)(omA + k0);
            f32x4 ob = *(const f32x4*)(omA + k0 + 4);
            f32x4 ta = *(const f32x4*)(tsA + k0);
            f32x4 tb = *(const f32x4*)(tsA + k0 + 4);
            bf16x8 v;
            v[0] = (__bf16)(oa[0] * ta[0]); v[1] = (__bf16)(oa[1] * ta[1]);
            v[2] = (__bf16)(oa[2] * ta[2]); v[3] = (__bf16)(oa[3] * ta[3]);
            v[4] = (__bf16)(ob[0] * tb[0]); v[5] = (__bf16)(ob[1] * tb[1]);
            v[6] = (__bf16)(ob[2] * tb[2]); v[7] = (__bf16)(ob[3] * tb[3]);
            Bh0[t] = v;
            oa = *(const f32x4*)(omB + k0);
            ob = *(const f32x4*)(omB + k0 + 4);
            ta = *(const f32x4*)(tsB + k0);
            tb = *(const f32x4*)(tsB + k0 + 4);
            v[0] = (__bf16)(oa[0] * ta[0]); v[1] = (__bf16)(oa[1] * ta[1]);
            v[2] = (__bf16)(oa[2] * ta[2]); v[3] = (__bf16)(oa[3] * ta[3]);
            v[4] = (__bf16)(ob[0] * tb[0]); v[5] = (__bf16)(ob[1] * tb[1]);
            v[6] = (__bf16)(ob[2] * tb[2]); v[7] = (__bf16)(ob[3] * tb[3]);
            Bh1[t] = v;
        }
    }

    // ---- layer 1: async-stage W1 per half-kb (rotated kb order); epilogue -> h2p ----
    {
        const float* om1a = onem + NS * H + s0 * H;
        const float* om1b = onem + NS * H + s1 * H;
#pragma unroll 1
        for (int i = 0; i < 16; ++i) {
            const int kb = (i + kb0) & 15;
            const __bf16* gpA = W1s + (size_t)kb * 16384 + (size_t)lane * 8;
            WAIT_LGKM0();   // prior phase's ds_reads done before overwrite
#pragma unroll
            for (int t = 0; t < 16; ++t)
                GLD_LDS16(gpA + t * 512, &wst[t * 512]);
            WAIT_VM0();
            f32x4 a00 = {0.f,0.f,0.f,0.f}, a01 = {0.f,0.f,0.f,0.f};
#pragma unroll
            for (int t = 0; t < 16; ++t) {
                bf16x8 w = *(const bf16x8*)&wst[t * 512 + lane * 8];
                a00 = __builtin_amdgcn_mfma_f32_16x16x32_bf16(w, Bh0[t], a00, 0, 0, 0);
                a01 = __builtin_amdgcn_mfma_f32_16x16x32_bf16(w, Bh1[t], a01, 0, 0, 0);
            }
            const __bf16* gpB = gpA + 16 * 512;
            WAIT_LGKM0();
#pragma unroll
            for (int t = 0; t < 16; ++t)
                GLD_LDS16(gpB + t * 512, &wst[t * 512]);
            WAIT_VM0();
            f32x4 a10 = {0.f,0.f,0.f,0.f}, a11 = {0.f,0.f,0.f,0.f};
#pragma unroll
            for (int t = 0; t < 16; ++t) {
                bf16x8 w = *(const bf16x8*)&wst[t * 512 + lane * 8];
                a10 = __builtin_amdgcn_mfma_f32_16x16x32_bf16(w, Bh0[t], a10, 0, 0, 0);
                a11 = __builtin_amdgcn_mfma_f32_16x16x32_bf16(w, Bh1[t], a11, 0, 0, 0);
            }
            const int c0 = kb * 32 + Q * 4, c1 = c0 + 16;
            float4 bi0 = *(const float4*)(sb1 + c0);
            float4 bi1 = *(const float4*)(sb1 + c1);
            float4 ga0 = *(const float4*)(om1a + c0);
            float4 ga1 = *(const float4*)(om1a + c1);
            float4 gb0 = *(const float4*)(om1b + c0);
            float4 gb1 = *(const float4*)(om1b + c1);
            bf16x4 v;
            v[0] = (__bf16)(ga0.x * __sinf(a00[0] + bi0.x));
            v[1] = (__bf16)(ga0.y * __sinf(a00[1] + bi0.y));
            v[2] = (__bf16)(ga0.z * __sinf(a00[2] + bi0.z));
            v[3] = (__bf16)(ga0.w * __sinf(a00[3] + bi0.w));
            *(bf16x4*)&h2p[L][c0] = v;
            v[0] = (__bf16)(ga1.x * __sinf(a10[0] + bi1.x));
            v[1] = (__bf16)(ga1.y * __sinf(a10[1] + bi1.y));
            v[2] = (__bf16)(ga1.z * __sinf(a10[2] + bi1.z));
            v[3] = (__bf16)(ga1.w * __sinf(a10[3] + bi1.w));
            *(bf16x4*)&h2p[L][c1] = v;
            v[0] = (__bf16)(gb0.x * __sinf(a01[0] + bi0.x));
            v[1] = (__bf16)(gb0.y * __sinf(a01[1] + bi0.y));
            v[2] = (__bf16)(gb0.z * __sinf(a01[2] + bi0.z));
            v[3] = (__bf16)(gb0.w * __sinf(a01[3] + bi0.w));
            *(bf16x4*)&h2p[16 + L][c0] = v;
            v[0] = (__bf16)(gb1.x * __sinf(a11[0] + bi1.x));
            v[1] = (__bf16)(gb1.y * __sinf(a11[1] + bi1.y));
            v[2] = (__bf16)(gb1.z * __sinf(a11[2] + bi1.z));
            v[3] = (__bf16)(gb1.w * __sinf(a11[3] + bi1.w));
            *(bf16x4*)&h2p[16 + L][c1] = v;
        }
    }
    __syncthreads();

    // ---- reload layer-2 B-frags (literal B-operand definition) ----
#pragma unroll
    for (int t = 0; t < 16; ++t) {
        Bh0[t] = *(const bf16x8*)&h2p[L][t * 32 + Q * 8];
        Bh1[t] = *(const bf16x8*)&h2p[16 + L][t * 32 + Q * 8];
    }

    // ---- layer 2: async-stage W2 per half-kb (rotated) + fused decoder ----
    float pA0 = 0.f, pA1 = 0.f, pA2 = 0.f;
    float pB0 = 0.f, pB1 = 0.f, pB2 = 0.f;
    {
        const float* om2a = onem + 2 * NS * H + s0 * H;
        const float* om2b = onem + 2 * NS * H + s1 * H;
#pragma unroll 1
        for (int i = 0; i < 16; ++i) {
            const int kb = (i + kb0) & 15;
            const __bf16* gpA = W2s + (size_t)kb * 16384 + (size_t)lane * 8;
            WAIT_LGKM0();
#pragma unroll
            for (int t = 0; t < 16; ++t)
                GLD_LDS16(gpA + t * 512, &wst[t * 512]);
            WAIT_VM0();
            f32x4 a00 = {0.f,0.f,0.f,0.f}, a01 = {0.f,0.f,0.f,0.f};
#pragma unroll
            for (int t = 0; t < 16; ++t) {
                bf16x8 w = *(const bf16x8*)&wst[t * 512 + lane * 8];
                a00 = __builtin_amdgcn_mfma_f32_16x16x32_bf16(w, Bh0[t], a00, 0, 0, 0);
                a01 = __builtin_amdgcn_mfma_f32_16x16x32_bf16(w, Bh1[t], a01, 0, 0, 0);
            }
            const __bf16* gpB = gpA + 16 * 512;
            WAIT_LGKM0();
#pragma unroll
            for (int t = 0; t < 16; ++t)
                GLD_LDS16(gpB + t * 512, &wst[t * 512]);
            WAIT_VM0();
            f32x4 a10 = {0.f,0.f,0.f,0.f}, a11 = {0.f,0.f,0.f,0.f};
#pragma unroll
            for (int t = 0; t < 16; ++t) {
                bf16x8 w = *(const bf16x8*)&wst[t * 512 + lane * 8];
                a10 = __builtin_amdgcn_mfma_f32_16x16x32_bf16(w, Bh0[t], a10, 0, 0, 0);
                a11 = __builtin_amdgcn_mfma_f32_16x16x32_bf16(w, Bh1[t], a11, 0, 0, 0);
            }
            const int c0 = kb * 32 + Q * 4, c1 = c0 + 16;
            float4 bi0 = *(const float4*)(sb2 + c0);
            float4 bi1 = *(const float4*)(sb2 + c1);
            float4 d00 = *(const float4*)(wnD + c0);
            float4 d10 = *(const float4*)(wnD + H + c0);
            float4 d20 = *(const float4*)(wnD + 2 * H + c0);
            float4 d01 = *(const float4*)(wnD + c1);
            float4 d11 = *(const float4*)(wnD + H + c1);
            float4 d21 = *(const float4*)(wnD + 2 * H + c1);
            float h;
            {
                float4 ga = *(const float4*)(om2a + c0);
                float4 gb = *(const float4*)(om2a + c1);
                h = ga.x * __sinf(a00[0] + bi0.x); pA0 += h * d00.x; pA1 += h * d10.x; pA2 += h * d20.x;
                h = ga.y * __sinf(a00[1] + bi0.y); pA0 += h * d00.y; pA1 += h * d10.y; pA2 += h * d20.y;
                h = ga.z * __sinf(a00[2] + bi0.z); pA0 += h * d00.z; pA1 += h * d10.z; pA2 += h * d20.z;
                h = ga.w * __sinf(a00[3] + bi0.w); pA0 += h * d00.w; pA1 += h * d10.w; pA2 += h * d20.w;
                h = gb.x * __sinf(a10[0] + bi1.x); pA0 += h * d01.x; pA1 += h * d11.x; pA2 += h * d21.x;
                h = gb.y * __sinf(a10[1] + bi1.y); pA0 += h * d01.y; pA1 += h * d11.y; pA2 += h * d21.y;
                h = gb.z * __sinf(a10[2] + bi1.z); pA0 += h * d01.z; pA1 += h * d11.z; pA2 += h * d21.z;
                h = gb.w * __sinf(a10[3] + bi1.w); pA0 += h * d01.w; pA1 += h * d11.w; pA2 += h * d21.w;
            }
            {
                float4 ga = *(const float4*)(om2b + c0);
                float4 gb = *(const float4*)(om2b + c1);
                h = ga.x * __sinf(a01[0] + bi0.x); pB0 += h * d00.x; pB1 += h * d10.x; pB2 += h * d20.x;
                h = ga.y * __sinf(a01[1] + bi0.y); pB0 += h * d00.y; pB1 += h * d10.y; pB2 += h * d20.y;
                h = ga.z * __sinf(a01[2] + bi0.z); pB0 += h * d00.z; pB1 += h * d10.z; pB2 += h * d20.z;
                h = ga.w * __sinf(a01[3] + bi0.w); pB0 += h * d00.w; pB1 += h * d10.w; pB2 += h * d20.w;
                h = gb.x * __sinf(a11[0] + bi1.x); pB0 += h * d01.x; pB1 += h * d11.x; pB2 += h * d21.x;
                h = gb.y * __sinf(a11[1] + bi1.y); pB0 += h * d01.y; pB1 += h * d11.y; pB2 += h * d21.y;
                h = gb.z * __sinf(a11[2] + bi1.z); pB0 += h * d01.z; pB1 += h * d11.z; pB2 += h * d21.z;
                h = gb.w * __sinf(a11[3] + bi1.w); pB0 += h * d01.w; pB1 += h * d11.w; pB2 += h * d21.w;
            }
        }
    }

    // reduce decoder partials over the 4 quads (same L)
    pA0 += __shfl_xor(pA0, 16, 64); pA0 += __shfl_xor(pA0, 32, 64);
    pA1 += __shfl_xor(pA1, 16, 64); pA1 += __shfl_xor(pA1, 32, 64);
    pA2 += __shfl_xor(pA2, 16, 64); pA2 += __shfl_xor(pA2, 32, 64);
    pB0 += __shfl_xor(pB0, 16, 64); pB0 += __shfl_xor(pB0, 32, 64);
    pB1 += __shfl_xor(pB1, 16, 64); pB1 += __shfl_xor(pB1, 32, 64);
    pB2 += __shfl_xor(pB2, 16, 64); pB2 += __shfl_xor(pB2, 32, 64);
    if (Q == 0) {
        const float d0 = db[0], d1 = db[1], d2 = db[2];
        dirs[r0 * 3 + 0] = 0.01f * (pA0 + d0);
        dirs[r0 * 3 + 1] = 0.01f * (pA1 + d1);
        dirs[r0 * 3 + 2] = 0.01f * (pA2 + d2);
        dirs[r1 * 3 + 0] = 0.01f * (pB0 + d0);
        dirs[r1 * 3 + 1] = 0.01f * (pB1 + d1);
        dirs[r1 * 3 + 2] = 0.01f * (pB2 + d2);
    }
}

// ---------------- K5: cumsum via wave scan (round-10 proven) ----------------
__global__ __launch_bounds__(256) void k_cumsum(const float* __restrict__ dirs,
                                                float* __restrict__ out)
{
    const int wid = blockIdx.x * 4 + (threadIdx.x >> 6);
    const int lane = threadIdx.x & 63;
    const int s = wid / 3, c = wid - 3 * s;
    const float* dp = dirs + (size_t)s * NV * 3 + c;
    float v0 = dp[lane * 3];
    float v1 = (lane < NV - 64) ? dp[(64 + lane) * 3] : 0.f;
#pragma unroll
    for (int off = 1; off < 64; off <<= 1) {
        float t = __shfl_up(v0, off, 64);
        if (lane >= off) v0 += t;
        t = __shfl_up(v1, off, 64);
        if (lane >= off) v1 += t;
    }
    float tot0 = __shfl(v0, 63, 64);
    v1 += tot0;
    float* op = out + (size_t)s * NPTS * 3 + c;
    if (lane == 0) op[0] = 0.f;
    op[(lane + 1) * 3] = v0;
    if (lane < NV - 64) op[(64 + lane + 1) * 3] = v1;
}

extern "C" void kernel_launch(void* const* d_in, const int* in_sizes, int n_in,
                              void* d_out, int out_size, void* d_ws, size_t ws_size,
                              hipStream_t stream)
{
    const float* sf  = (const float*)d_in[0];
    const float* mv0 = (const float*)d_in[1];  const float* mg0 = (const float*)d_in[2];  const float* mb0 = (const float*)d_in[3];
    const float* mv1 = (const float*)d_in[4];  const float* mg1 = (const float*)d_in[5];  const float* mb1 = (const float*)d_in[6];
    const float* mv2 = (const float*)d_in[7];  const float* mg2 = (const float*)d_in[8];  const float* mb2 = (const float*)d_in[9];
    const float* sv0 = (const float*)d_in[10]; const float* sg0 = (const float*)d_in[11]; const float* sb0 = (const float*)d_in[12];
    const float* sv1 = (const float*)d_in[13]; const float* sg1 = (const float*)d_in[14]; const float* sb1 = (const float*)d_in[15];
    const float* sv2 = (const float*)d_in[16]; const float* sg2 = (const float*)d_in[17]; const float* sb2 = (const float*)d_in[18];
    const float* dv  = (const float*)d_in[19]; const float* dg  = (const float*)d_in[20]; const float* dbv = (const float*)d_in[21];

    float* ws = (float*)d_ws;
    float* wnM0  = ws;                 // 32768
    float* wnM1  = ws + 32768;         // 294912
    float* wnM2  = ws + 327680;        // 294912
    float* wnD   = ws + 622592;        // 1536
    float* s0sin = ws + 624128;        // 50688
    float* onem  = ws + 674816;        // 1572864
    float* dirs  = ws + 2247680;       // 304128
    __bf16* W1s  = (__bf16*)(ws + 2551808);   // 512 KB (swizzled)
    __bf16* W2s  = W1s + 262144;              // 512 KB (swizzled)

    hipLaunchKernelGGL(k_wnorm, dim3(641 + 198), dim3(256), 0, stream,
                       mv0, mg0, mv1, mg1, mv2, mg2, sv0, sg0, sb0,
                       sv1, sg1, sv2, sg2, dv, dg,
                       wnM0, wnM1, wnM2, W1s, W2s, wnD, s0sin);
    hipLaunchKernelGGL(k_mod, dim3(256), dim3(256), 0, stream,
                       sf, wnM0, mb0, wnM1, mb1, wnM2, mb2, onem);
    hipLaunchKernelGGL(k_main, dim3((NS * NV) / 32), dim3(64), 0, stream,
                       W1s, W2s, wnD, sb1, sb2, dbv, s0sin, onem, dirs);
    hipLaunchKernelGGL(k_cumsum, dim3(768), dim3(256), 0, stream, dirs, (float*)d_out);
}

// Round 17
// 469.339 us; speedup vs baseline: 1.0218x; 1.0218x over previous
//
#include <hip/hip_runtime.h>
#include <math.h>

#define NS 1024
#define NV 99
#define NPTS 100
#define H 512

typedef __bf16 bf16x8 __attribute__((ext_vector_type(8)));
typedef __bf16 bf16x4 __attribute__((ext_vector_type(4)));
typedef float f32x4 __attribute__((ext_vector_type(4)));

// async 16B-per-lane global->LDS copy; LDS dest is wave-uniform base + lane*16
#define GLD_LDS16(gp, lp) __builtin_amdgcn_global_load_lds(                 \
    (const __attribute__((address_space(1))) void*)(gp),                    \
    (__attribute__((address_space(3))) void*)(lp), 16, 0, 0)
#define WAIT_VM0()   __builtin_amdgcn_s_waitcnt(0x0f70)   // vmcnt(0) only
#define WAIT_LGKM0() __builtin_amdgcn_s_waitcnt(0xc07f)   // lgkmcnt(0) only

// ---------------- K1: weight norm, wave-per-row, + folded s0 table ----------------
// Blocks 0..640: 4 weight rows per block (one wave per row, shfl_xor reduce,
// no LDS / no barriers). Blocks 641..838: the s0sin table (old k_s0).
// mod weights row-major; siren W1/W2 bf16 MFMA-fragment-swizzled:
// swz[((ct*16 + t)*64 + Q*16 + L)*8 + j] = W[ct*16+L][t*32+Q*8+j]
__global__ __launch_bounds__(256) void k_wnorm(
    const float* __restrict__ mv0, const float* __restrict__ mg0,
    const float* __restrict__ mv1, const float* __restrict__ mg1,
    const float* __restrict__ mv2, const float* __restrict__ mg2,
    const float* __restrict__ sv0, const float* __restrict__ sg0,
    const float* __restrict__ sb0,
    const float* __restrict__ sv1, const float* __restrict__ sg1,
    const float* __restrict__ sv2, const float* __restrict__ sg2,
    const float* __restrict__ dv,  const float* __restrict__ dg,
    float* __restrict__ wnM0, float* __restrict__ wnM1, float* __restrict__ wnM2,
    __bf16* __restrict__ W1s, __bf16* __restrict__ W2s, float* __restrict__ wnD,
    float* __restrict__ s0sin)
{
    const int b = blockIdx.x, tid = threadIdx.x;
    if (b >= 641) {   // folded k_s0
        int idx = (b - 641) * 256 + tid;
        if (idx < NV * H) {
            int p = idx >> 9, j = idx & 511;
            float v = sv0[j];
            float w = sg0[j] * v * rsqrtf(v * v);
            float t = (float)p / 99.0f;
            s0sin[idx] = __sinf(30.0f * (t * w + sb0[j]));
        }
        return;
    }
    const int rid = b * 4 + (tid >> 6);
    const int lane = tid & 63;
    if (rid >= 2563) return;

    const float* src; const float* g; int len, j;
    float* dstf = nullptr; __bf16* dstb = nullptr;
    if (rid < 512)       { j = rid;        src = mv0 + j*64;  g = mg0; dstf = wnM0 + j*64;  len = 64;  }
    else if (rid < 1024) { j = rid - 512;  src = mv1 + j*576; g = mg1; dstf = wnM1 + j*576; len = 576; }
    else if (rid < 1536) { j = rid - 1024; src = mv2 + j*576; g = mg2; dstf = wnM2 + j*576; len = 576; }
    else if (rid < 2048) { j = rid - 1536; src = sv1 + j*512; g = sg1; dstb = W1s;          len = 512; }
    else if (rid < 2560) { j = rid - 2048; src = sv2 + j*512; g = sg2; dstb = W2s;          len = 512; }
    else                 { j = rid - 2560; src = dv  + j*512; g = dg;  dstf = wnD + j*512;  len = 512; }

    float ss = 0.f;
    for (int k = lane; k < len; k += 64) { float v = src[k]; ss += v * v; }
#pragma unroll
    for (int o = 1; o < 64; o <<= 1) ss += __shfl_xor(ss, o, 64);
    const float sc = g[j] * rsqrtf(ss);

    if (dstb) {
        for (int k = lane; k < len; k += 64) {
            int f  = (j >> 4) * 16 + (k >> 5);
            int el = ((f * 64) + ((k >> 3) & 3) * 16 + (j & 15)) * 8 + (k & 7);
            dstb[el] = (__bf16)(src[k] * sc);
        }
    } else {
        for (int k = lane; k < len; k += 64) dstf[k] = src[k] * sc;
    }
}

// ---------------- K3: modulation branch, 4 strands per block (round-3 proven) ----------------
__global__ __launch_bounds__(256) void k_mod(
    const float* __restrict__ sf,
    const float* __restrict__ wnM0, const float* __restrict__ mb0,
    const float* __restrict__ wnM1, const float* __restrict__ mb1,
    const float* __restrict__ wnM2, const float* __restrict__ mb2,
    float* __restrict__ onem)
{
    const int g0 = blockIdx.x * 4, tid = threadIdx.x;
    __shared__ float z[4][576];   // [strand][64 feat | 512 hidden]

    for (int idx = tid; idx < 4 * 64; idx += 256)
        z[idx >> 6][idx & 63] = sf[(g0 + (idx >> 6)) * 64 + (idx & 63)];
    __syncthreads();

    float mreg[2][4];
    // ---- layer 0 (in=64) ----
#pragma unroll
    for (int r = 0; r < 2; ++r) {
        const int j = tid + 256 * r;
        const float* wr = wnM0 + j * 64;
        float acc[4] = {0.f, 0.f, 0.f, 0.f};
#pragma unroll
        for (int k = 0; k < 64; k += 4) {
            float4 w = *(const float4*)(wr + k);
#pragma unroll
            for (int g = 0; g < 4; ++g) {
                float4 zv = *(const float4*)&z[g][k];
                acc[g] += zv.x * w.x + zv.y * w.y + zv.z * w.z + zv.w * w.w;
            }
        }
        const float b = mb0[j];
#pragma unroll
        for (int g = 0; g < 4; ++g) {
            float a = acc[g] + b;
            float m = a / (1.f + __expf(-a));
            onem[(g0 + g) * H + j] = 1.f - m;
            mreg[r][g] = m;
        }
    }
    __syncthreads();
#pragma unroll
    for (int r = 0; r < 2; ++r)
#pragma unroll
        for (int g = 0; g < 4; ++g) z[g][64 + tid + 256 * r] = mreg[r][g];
    __syncthreads();

    // ---- layer 1 (in=576) ----
#pragma unroll
    for (int r = 0; r < 2; ++r) {
        const int j = tid + 256 * r;
        const float* wr = wnM1 + j * 576;
        float acc[4] = {0.f, 0.f, 0.f, 0.f};
        for (int k = 0; k < 576; k += 4) {
            float4 w = *(const float4*)(wr + k);
#pragma unroll
            for (int g = 0; g < 4; ++g) {
                float4 zv = *(const float4*)&z[g][k];
                acc[g] += zv.x * w.x + zv.y * w.y + zv.z * w.z + zv.w * w.w;
            }
        }
        const float b = mb1[j];
#pragma unroll
        for (int g = 0; g < 4; ++g) {
            float a = acc[g] + b;
            float m = a / (1.f + __expf(-a));
            onem[NS * H + (g0 + g) * H + j] = 1.f - m;
            mreg[r][g] = m;
        }
    }
    __syncthreads();
#pragma unroll
    for (int r = 0; r < 2; ++r)
#pragma unroll
        for (int g = 0; g < 4; ++g) z[g][64 + tid + 256 * r] = mreg[r][g];
    __syncthreads();

    // ---- layer 2 (in=576) ----
#pragma unroll
    for (int r = 0; r < 2; ++r) {
        const int j = tid + 256 * r;
        const float* wr = wnM2 + j * 576;
        float acc[4] = {0.f, 0.f, 0.f, 0.f};
        for (int k = 0; k < 576; k += 4) {
            float4 w = *(const float4*)(wr + k);
#pragma unroll
            for (int g = 0; g < 4; ++g) {
                float4 zv = *(const float4*)&z[g][k];
                acc[g] += zv.x * w.x + zv.y * w.y + zv.z * w.z + zv.w * w.w;
            }
        }
        const float b = mb2[j];
#pragma unroll
        for (int g = 0; g < 4; ++g) {
            float a = acc[g] + b;
            float m = a / (1.f + __expf(-a));
            onem[2 * NS * H + (g0 + g) * H + j] = 1.f - m;
        }
    }
}

// ---------------- K4: main fused siren layers 1,2 + decoder (round-10/15 proven) ----------------
// 1 wave/block, 32 rows, operand-swap MFMA, row-major padded LDS h2 handoff.
// W stream via async global_load_lds (16B/lane) into 16 KB LDS staging:
// 16 fire-and-forget loads per phase -> ONE latency drain per 16 KB tile.
__global__ __launch_bounds__(64, 1) void k_main(
    const __bf16* __restrict__ W1s, const __bf16* __restrict__ W2s,
    const float* __restrict__ wnD, const float* __restrict__ sb1,
    const float* __restrict__ sb2, const float* __restrict__ db,
    const float* __restrict__ s0sin, const float* __restrict__ onem,
    float* __restrict__ dirs)
{
    __shared__ __attribute__((aligned(16))) __bf16 h2p[32][520];  // 33280 B
    __shared__ __attribute__((aligned(16))) __bf16 wst[8192];     // 16 KB staging
    const int lane = threadIdx.x;
    const int L = lane & 15, Q = lane >> 4;
    const int base = blockIdx.x * 32;
    const int r0 = base + L, r1 = r0 + 16;
    const int s0 = r0 / 99, p0 = r0 - s0 * 99;
    const int s1 = r1 / 99, p1 = r1 - s1 * 99;

    // ---- build layer-1 B-frags: Bh[t][j] = h1[r][t*32+Q*8+j] ----
    bf16x8 Bh0[16], Bh1[16];
    {
        const float* omA = onem + s0 * H;
        const float* tsA = s0sin + p0 * H;
        const float* omB = onem + s1 * H;
        const float* tsB = s0sin + p1 * H;
#pragma unroll
        for (int t = 0; t < 16; ++t) {
            const int k0 = t * 32 + Q * 8;
            f32x4 oa = *(const f32x4*)(omA + k0);
            f32x4 ob = *(const f32x4*)(omA + k0 + 4);
            f32x4 ta = *(const f32x4*)(tsA + k0);
            f32x4 tb = *(const f32x4*)(tsA + k0 + 4);
            bf16x8 v;
            v[0] = (__bf16)(oa[0] * ta[0]); v[1] = (__bf16)(oa[1] * ta[1]);
            v[2] = (__bf16)(oa[2] * ta[2]); v[3] = (__bf16)(oa[3] * ta[3]);
            v[4] = (__bf16)(ob[0] * tb[0]); v[5] = (__bf16)(ob[1] * tb[1]);
            v[6] = (__bf16)(ob[2] * tb[2]); v[7] = (__bf16)(ob[3] * tb[3]);
            Bh0[t] = v;
            oa = *(const f32x4*)(omB + k0);
            ob = *(const f32x4*)(omB + k0 + 4);
            ta = *(const f32x4*)(tsB + k0);
            tb = *(const f32x4*)(tsB + k0 + 4);
            v[0] = (__bf16)(oa[0] * ta[0]); v[1] = (__bf16)(oa[1] * ta[1]);
            v[2] = (__bf16)(oa[2] * ta[2]); v[3] = (__bf16)(oa[3] * ta[3]);
            v[4] = (__bf16)(ob[0] * tb[0]); v[5] = (__bf16)(ob[1] * tb[1]);
            v[6] = (__bf16)(ob[2] * tb[2]); v[7] = (__bf16)(ob[3] * tb[3]);
            Bh1[t] = v;
        }
    }

    // ---- layer 1: async-stage W1 per half-kb; epilogue -> h2p ----
    {
        const float* om1a = onem + NS * H + s0 * H;
        const float* om1b = onem + NS * H + s1 * H;
#pragma unroll 1
        for (int kb = 0; kb < 16; ++kb) {
            const __bf16* gpA = W1s + (size_t)kb * 16384 + (size_t)lane * 8;
            WAIT_LGKM0();   // prior phase's ds_reads done before overwrite
#pragma unroll
            for (int t = 0; t < 16; ++t)
                GLD_LDS16(gpA + t * 512, &wst[t * 512]);
            WAIT_VM0();
            f32x4 a00 = {0.f,0.f,0.f,0.f}, a01 = {0.f,0.f,0.f,0.f};
#pragma unroll
            for (int t = 0; t < 16; ++t) {
                bf16x8 w = *(const bf16x8*)&wst[t * 512 + lane * 8];
                a00 = __builtin_amdgcn_mfma_f32_16x16x32_bf16(w, Bh0[t], a00, 0, 0, 0);
                a01 = __builtin_amdgcn_mfma_f32_16x16x32_bf16(w, Bh1[t], a01, 0, 0, 0);
            }
            const __bf16* gpB = gpA + 16 * 512;
            WAIT_LGKM0();
#pragma unroll
            for (int t = 0; t < 16; ++t)
                GLD_LDS16(gpB + t * 512, &wst[t * 512]);
            WAIT_VM0();
            f32x4 a10 = {0.f,0.f,0.f,0.f}, a11 = {0.f,0.f,0.f,0.f};
#pragma unroll
            for (int t = 0; t < 16; ++t) {
                bf16x8 w = *(const bf16x8*)&wst[t * 512 + lane * 8];
                a10 = __builtin_amdgcn_mfma_f32_16x16x32_bf16(w, Bh0[t], a10, 0, 0, 0);
                a11 = __builtin_amdgcn_mfma_f32_16x16x32_bf16(w, Bh1[t], a11, 0, 0, 0);
            }
            const int c0 = kb * 32 + Q * 4, c1 = c0 + 16;
            float4 bi0 = *(const float4*)(sb1 + c0);
            float4 bi1 = *(const float4*)(sb1 + c1);
            float4 ga0 = *(const float4*)(om1a + c0);
            float4 ga1 = *(const float4*)(om1a + c1);
            float4 gb0 = *(const float4*)(om1b + c0);
            float4 gb1 = *(const float4*)(om1b + c1);
            bf16x4 v;
            v[0] = (__bf16)(ga0.x * __sinf(a00[0] + bi0.x));
            v[1] = (__bf16)(ga0.y * __sinf(a00[1] + bi0.y));
            v[2] = (__bf16)(ga0.z * __sinf(a00[2] + bi0.z));
            v[3] = (__bf16)(ga0.w * __sinf(a00[3] + bi0.w));
            *(bf16x4*)&h2p[L][c0] = v;
            v[0] = (__bf16)(ga1.x * __sinf(a10[0] + bi1.x));
            v[1] = (__bf16)(ga1.y * __sinf(a10[1] + bi1.y));
            v[2] = (__bf16)(ga1.z * __sinf(a10[2] + bi1.z));
            v[3] = (__bf16)(ga1.w * __sinf(a10[3] + bi1.w));
            *(bf16x4*)&h2p[L][c1] = v;
            v[0] = (__bf16)(gb0.x * __sinf(a01[0] + bi0.x));
            v[1] = (__bf16)(gb0.y * __sinf(a01[1] + bi0.y));
            v[2] = (__bf16)(gb0.z * __sinf(a01[2] + bi0.z));
            v[3] = (__bf16)(gb0.w * __sinf(a01[3] + bi0.w));
            *(bf16x4*)&h2p[16 + L][c0] = v;
            v[0] = (__bf16)(gb1.x * __sinf(a11[0] + bi1.x));
            v[1] = (__bf16)(gb1.y * __sinf(a11[1] + bi1.y));
            v[2] = (__bf16)(gb1.z * __sinf(a11[2] + bi1.z));
            v[3] = (__bf16)(gb1.w * __sinf(a11[3] + bi1.w));
            *(bf16x4*)&h2p[16 + L][c1] = v;
        }
    }
    __syncthreads();

    // ---- reload layer-2 B-frags (literal B-operand definition) ----
#pragma unroll
    for (int t = 0; t < 16; ++t) {
        Bh0[t] = *(const bf16x8*)&h2p[L][t * 32 + Q * 8];
        Bh1[t] = *(const bf16x8*)&h2p[16 + L][t * 32 + Q * 8];
    }

    // ---- layer 2: async-stage W2 per half-kb + fused decoder ----
    float pA0 = 0.f, pA1 = 0.f, pA2 = 0.f;
    float pB0 = 0.f, pB1 = 0.f, pB2 = 0.f;
    {
        const float* om2a = onem + 2 * NS * H + s0 * H;
        const float* om2b = onem + 2 * NS * H + s1 * H;
#pragma unroll 1
        for (int kb = 0; kb < 16; ++kb) {
            const __bf16* gpA = W2s + (size_t)kb * 16384 + (size_t)lane * 8;
            WAIT_LGKM0();
#pragma unroll
            for (int t = 0; t < 16; ++t)
                GLD_LDS16(gpA + t * 512, &wst[t * 512]);
            WAIT_VM0();
            f32x4 a00 = {0.f,0.f,0.f,0.f}, a01 = {0.f,0.f,0.f,0.f};
#pragma unroll
            for (int t = 0; t < 16; ++t) {
                bf16x8 w = *(const bf16x8*)&wst[t * 512 + lane * 8];
                a00 = __builtin_amdgcn_mfma_f32_16x16x32_bf16(w, Bh0[t], a00, 0, 0, 0);
                a01 = __builtin_amdgcn_mfma_f32_16x16x32_bf16(w, Bh1[t], a01, 0, 0, 0);
            }
            const __bf16* gpB = gpA + 16 * 512;
            WAIT_LGKM0();
#pragma unroll
            for (int t = 0; t < 16; ++t)
                GLD_LDS16(gpB + t * 512, &wst[t * 512]);
            WAIT_VM0();
            f32x4 a10 = {0.f,0.f,0.f,0.f}, a11 = {0.f,0.f,0.f,0.f};
#pragma unroll
            for (int t = 0; t < 16; ++t) {
                bf16x8 w = *(const bf16x8*)&wst[t * 512 + lane * 8];
                a10 = __builtin_amdgcn_mfma_f32_16x16x32_bf16(w, Bh0[t], a10, 0, 0, 0);
                a11 = __builtin_amdgcn_mfma_f32_16x16x32_bf16(w, Bh1[t], a11, 0, 0, 0);
            }
            const int c0 = kb * 32 + Q * 4, c1 = c0 + 16;
            float4 bi0 = *(const float4*)(sb2 + c0);
            float4 bi1 = *(const float4*)(sb2 + c1);
            float4 d00 = *(const float4*)(wnD + c0);
            float4 d10 = *(const float4*)(wnD + H + c0);
            float4 d20 = *(const float4*)(wnD + 2 * H + c0);
            float4 d01 = *(const float4*)(wnD + c1);
            float4 d11 = *(const float4*)(wnD + H + c1);
            float4 d21 = *(const float4*)(wnD + 2 * H + c1);
            float h;
            {
                float4 ga = *(const float4*)(om2a + c0);
                float4 gb = *(const float4*)(om2a + c1);
                h = ga.x * __sinf(a00[0] + bi0.x); pA0 += h * d00.x; pA1 += h * d10.x; pA2 += h * d20.x;
                h = ga.y * __sinf(a00[1] + bi0.y); pA0 += h * d00.y; pA1 += h * d10.y; pA2 += h * d20.y;
                h = ga.z * __sinf(a00[2] + bi0.z); pA0 += h * d00.z; pA1 += h * d10.z; pA2 += h * d20.z;
                h = ga.w * __sinf(a00[3] + bi0.w); pA0 += h * d00.w; pA1 += h * d10.w; pA2 += h * d20.w;
                h = gb.x * __sinf(a10[0] + bi1.x); pA0 += h * d01.x; pA1 += h * d11.x; pA2 += h * d21.x;
                h = gb.y * __sinf(a10[1] + bi1.y); pA0 += h * d01.y; pA1 += h * d11.y; pA2 += h * d21.y;
                h = gb.z * __sinf(a10[2] + bi1.z); pA0 += h * d01.z; pA1 += h * d11.z; pA2 += h * d21.z;
                h = gb.w * __sinf(a10[3] + bi1.w); pA0 += h * d01.w; pA1 += h * d11.w; pA2 += h * d21.w;
            }
            {
                float4 ga = *(const float4*)(om2b + c0);
                float4 gb = *(const float4*)(om2b + c1);
                h = ga.x * __sinf(a01[0] + bi0.x); pB0 += h * d00.x; pB1 += h * d10.x; pB2 += h * d20.x;
                h = ga.y * __sinf(a01[1] + bi0.y); pB0 += h * d00.y; pB1 += h * d10.y; pB2 += h * d20.y;
                h = ga.z * __sinf(a01[2] + bi0.z); pB0 += h * d00.z; pB1 += h * d10.z; pB2 += h * d20.z;
                h = ga.w * __sinf(a01[3] + bi0.w); pB0 += h * d00.w; pB1 += h * d10.w; pB2 += h * d20.w;
                h = gb.x * __sinf(a11[0] + bi1.x); pB0 += h * d01.x; pB1 += h * d11.x; pB2 += h * d21.x;
                h = gb.y * __sinf(a11[1] + bi1.y); pB0 += h * d01.y; pB1 += h * d11.y; pB2 += h * d21.y;
                h = gb.z * __sinf(a11[2] + bi1.z); pB0 += h * d01.z; pB1 += h * d11.z; pB2 += h * d21.z;
                h = gb.w * __sinf(a11[3] + bi1.w); pB0 += h * d01.w; pB1 += h * d11.w; pB2 += h * d21.w;
            }
        }
    }

    // reduce decoder partials over the 4 quads (same L)
    pA0 += __shfl_xor(pA0, 16, 64); pA0 += __shfl_xor(pA0, 32, 64);
    pA1 += __shfl_xor(pA1, 16, 64); pA1 += __shfl_xor(pA1, 32, 64);
    pA2 += __shfl_xor(pA2, 16, 64); pA2 += __shfl_xor(pA2, 32, 64);
    pB0 += __shfl_xor(pB0, 16, 64); pB0 += __shfl_xor(pB0, 32, 64);
    pB1 += __shfl_xor(pB1, 16, 64); pB1 += __shfl_xor(pB1, 32, 64);
    pB2 += __shfl_xor(pB2, 16, 64); pB2 += __shfl_xor(pB2, 32, 64);
    if (Q == 0) {
        const float d0 = db[0], d1 = db[1], d2 = db[2];
        dirs[r0 * 3 + 0] = 0.01f * (pA0 + d0);
        dirs[r0 * 3 + 1] = 0.01f * (pA1 + d1);
        dirs[r0 * 3 + 2] = 0.01f * (pA2 + d2);
        dirs[r1 * 3 + 0] = 0.01f * (pB0 + d0);
        dirs[r1 * 3 + 1] = 0.01f * (pB1 + d1);
        dirs[r1 * 3 + 2] = 0.01f * (pB2 + d2);
    }
}

// ---------------- K5: cumsum via wave scan (round-10 proven) ----------------
__global__ __launch_bounds__(256) void k_cumsum(const float* __restrict__ dirs,
                                                float* __restrict__ out)
{
    const int wid = blockIdx.x * 4 + (threadIdx.x >> 6);
    const int lane = threadIdx.x & 63;
    const int s = wid / 3, c = wid - 3 * s;
    const float* dp = dirs + (size_t)s * NV * 3 + c;
    float v0 = dp[lane * 3];
    float v1 = (lane < NV - 64) ? dp[(64 + lane) * 3] : 0.f;
#pragma unroll
    for (int off = 1; off < 64; off <<= 1) {
        float t = __shfl_up(v0, off, 64);
        if (lane >= off) v0 += t;
        t = __shfl_up(v1, off, 64);
        if (lane >= off) v1 += t;
    }
    float tot0 = __shfl(v0, 63, 64);
    v1 += tot0;
    float* op = out + (size_t)s * NPTS * 3 + c;
    if (lane == 0) op[0] = 0.f;
    op[(lane + 1) * 3] = v0;
    if (lane < NV - 64) op[(64 + lane + 1) * 3] = v1;
}

extern "C" void kernel_launch(void* const* d_in, const int* in_sizes, int n_in,
                              void* d_out, int out_size, void* d_ws, size_t ws_size,
                              hipStream_t stream)
{
    const float* sf  = (const float*)d_in[0];
    const float* mv0 = (const float*)d_in[1];  const float* mg0 = (const float*)d_in[2];  const float* mb0 = (const float*)d_in[3];
    const float* mv1 = (const float*)d_in[4];  const float* mg1 = (const float*)d_in[5];  const float* mb1 = (const float*)d_in[6];
    const float* mv2 = (const float*)d_in[7];  const float* mg2 = (const float*)d_in[8];  const float* mb2 = (const float*)d_in[9];
    const float* sv0 = (const float*)d_in[10]; const float* sg0 = (const float*)d_in[11]; const float* sb0 = (const float*)d_in[12];
    const float* sv1 = (const float*)d_in[13]; const float* sg1 = (const float*)d_in[14]; const float* sb1 = (const float*)d_in[15];
    const float* sv2 = (const float*)d_in[16]; const float* sg2 = (const float*)d_in[17]; const float* sb2 = (const float*)d_in[18];
    const float* dv  = (const float*)d_in[19]; const float* dg  = (const float*)d_in[20]; const float* dbv = (const float*)d_in[21];

    float* ws = (float*)d_ws;
    float* wnM0  = ws;                 // 32768
    float* wnM1  = ws + 32768;         // 294912
    float* wnM2  = ws + 327680;        // 294912
    float* wnD   = ws + 622592;        // 1536
    float* s0sin = ws + 624128;        // 50688
    float* onem  = ws + 674816;        // 1572864
    float* dirs  = ws + 2247680;       // 304128
    __bf16* W1s  = (__bf16*)(ws + 2551808);   // 512 KB (swizzled)
    __bf16* W2s  = W1s + 262144;              // 512 KB (swizzled)

    hipLaunchKernelGGL(k_wnorm, dim3(641 + 198), dim3(256), 0, stream,
                       mv0, mg0, mv1, mg1, mv2, mg2, sv0, sg0, sb0,
                       sv1, sg1, sv2, sg2, dv, dg,
                       wnM0, wnM1, wnM2, W1s, W2s, wnD, s0sin);
    hipLaunchKernelGGL(k_mod, dim3(256), dim3(256), 0, stream,
                       sf, wnM0, mb0, wnM1, mb1, wnM2, mb2, onem);
    hipLaunchKernelGGL(k_main, dim3((NS * NV) / 32), dim3(64), 0, stream,
                       W1s, W2s, wnD, sb1, sb2, dbv, s0sin, onem, dirs);
    hipLaunchKernelGGL(k_cumsum, dim3(768), dim3(256), 0, stream, dirs, (float*)d_out);
}